// Round 3
// baseline (59.234 us; speedup 1.0000x reference)
//
#include <hip/hip_runtime.h>
#include <hip/hip_bf16.h>
#include <stdint.h>

// KANLinear: y[b,o] = sum_{d,k} coeff[b,d,k]*values[o,d,k] + xc@skip_w^T + skip_b
// Reformulated: Vp[o,d*16+k] = values[o,d,k] + grid[k]*skip_w[o,d]  (prep)
//               y = A @ Vp^T + skip_b  (bf16 MFMA GEMM, M=8192 N=256 K=4096)
// Round 3: wave-tile 64x64 (LDS intensity 16->32 FLOP/elem), BM=BN=128,
//          BK=64 (conflict-free 128B rows), K-split 4 + f32 atomics,
//          512 blocks = 2/CU, dbuf LDS 64KB, single barrier per iter.

#define D_DIM  256
#define O_DIM  256
#define BM     128
#define BN     128
#define BK     64
#define KSPLIT 4
#define ITERS  16            // (4096/KSPLIT)/BK
#define NTHREADS 256

typedef __attribute__((ext_vector_type(8))) short bf16x8;
typedef __attribute__((ext_vector_type(4))) float f32x4;

// ---------------------------------------------------------------------------
// Prep: Vp[o][kflat] = values[o][d][k] + grid[k]*skip_w[o][d], bf16.
// Layout: tile (ntile = o>>7, kt = kflat>>6) = 128 rows(n=o&127) x 64 cols,
// 1024 chunks of 16B; chunk (n, k8=(kflat>>3)&7) at slot n*8 + (k8^(n&7)).
// GEMM B-staging is a linear global_load_lds copy; swizzled ds_read_b128 of
// row-fragments is conflict-free (rule 21: inverse-swizzled src + swz read).
// ---------------------------------------------------------------------------
__global__ __launch_bounds__(256) void kan_prep(
    const float* __restrict__ values,   // [O][D][K]
    const float* __restrict__ skip_w,   // [O][D]
    const float* __restrict__ gknots,   // [K]
    unsigned short* __restrict__ Vp)    // 2 MB bf16, swizzled-tiled
{
    int tid = blockIdx.x * blockDim.x + threadIdx.x;    // 0..131071
    int e = tid * 8;
    int o = e >> 12;
    int kflat = e & 4095;
    float sw = skip_w[(o << 8) | (kflat >> 4)];
    int kmod = kflat & 15;                              // 0 or 8

    const float4* vp4 = reinterpret_cast<const float4*>(values + e);
    float4 v0 = vp4[0], v1 = vp4[1];
    float f[8] = {v0.x, v0.y, v0.z, v0.w, v1.x, v1.y, v1.z, v1.w};
    unsigned int w[4];
#pragma unroll
    for (int j = 0; j < 4; ++j) {
        float2 ab;
        ab.x = f[2*j]     + gknots[kmod + 2*j]     * sw;
        ab.y = f[2*j + 1] + gknots[kmod + 2*j + 1] * sw;
        __hip_bfloat162 p2 = __float22bfloat162_rn(ab);
        __builtin_memcpy(&w[j], &p2, 4);
    }

    int ntile = o >> 7, n = o & 127;
    int kt = kflat >> 6, k8 = (kflat >> 3) & 7;
    int slot = n * 8 + (k8 ^ (n & 7));
    size_t dst = ((size_t)(ntile * 64 + kt) * 1024 + (size_t)slot) * 8;
    *reinterpret_cast<uint4*>(Vp + dst) = make_uint4(w[0], w[1], w[2], w[3]);
}

// ---------------------------------------------------------------------------
// GEMM: BM=BN=128, BK=64, 4 waves each owning a 64x64 wave-tile (acc[4][4]).
// K-split 4: block ks handles K = [ks*1024, (ks+1)*1024); partials combined
// with f32 atomics (out pre-zeroed). skip_b added by ks==0 blocks only.
// ---------------------------------------------------------------------------
__global__ __launch_bounds__(NTHREADS) void kan_gemm(
    const float* __restrict__ x,          // [B][D] f32
    const unsigned short* __restrict__ Vp,
    const float* __restrict__ skip_b,     // [O]
    float* __restrict__ out)              // [B][O] f32 (zero-initialized)
{
    __shared__ unsigned short As[2][BM * BK];   // 2 x 16 KB
    __shared__ unsigned short Bs[2][BN * BK];   // 2 x 16 KB

    const int t    = threadIdx.x;
    const int lane = t & 63;
    const int wid  = t >> 6;
    const int wm   = wid >> 1;         // wave row 0..1 (64 rows each)
    const int wn   = wid & 1;          // wave col 0..1 (64 cols each)
    const int l15  = lane & 15;
    const int lhi  = lane >> 4;        // 0..3

    const int bid = (int)blockIdx.x;
    const int ks  = bid & 3;                       // K-split slice
    const int nt  = (bid >> 2) & 1;                // N tile
    const int mt  = bid >> 3;                      // M tile 0..63
    const int bm0 = mt * BM;
    const int oc0 = nt * BN;
    const int kt0 = ks * ITERS;                    // global BK-tile base

    // A-stage: thread handles row ab, d-pair {ad2, ad2+1} per iter
    const int ab  = t >> 1;            // 0..127
    const int ad2 = (t & 1) * 2;       // 0 or 2
    const float* xp = x + (size_t)(bm0 + ab) * D_DIM + ks * 64 + ad2;

    char* arow[2] = { (char*)&As[0][0] + ab * 128, (char*)&As[1][0] + ab * 128 };
    const int cs0 = ((ad2 * 2)     ^ (ab & 7)) * 16;
    const int cs1 = ((ad2 * 2 + 1) ^ (ab & 7)) * 16;
    const int cs2 = ((ad2 * 2 + 2) ^ (ab & 7)) * 16;
    const int cs3 = ((ad2 * 2 + 3) ^ (ab & 7)) * 16;

    f32x4 acc[4][4] = {};

    // one x value -> 16 bf16 interp coeffs (8 dwords), pair at knots li,li+1
    auto buildwd = [&](float xv, unsigned int* wd) {
        float xc = fminf(1.f, fmaxf(-1.f, xv));
        float tt = (xc + 1.f) * 7.5f;            // (xc - g0)/h, h = 2/15
        int li = (int)tt;
        li = li > 14 ? 14 : li;
        float w1 = tt - (float)li;
        float2 cw; cw.x = 1.f - w1; cw.y = w1;
        __hip_bfloat162 p2 = __float22bfloat162_rn(cw);   // v_cvt_pk_bf16_f32
        unsigned int pk;
        __builtin_memcpy(&pk, &p2, 4);
        unsigned long long w64 = (unsigned long long)pk << ((li & 1) * 16);
        unsigned int lo = (unsigned int)w64;
        unsigned int hi = (unsigned int)(w64 >> 32);
        int jl = li >> 1;
#pragma unroll
        for (int j = 0; j < 8; ++j)
            wd[j] = (j == jl) ? lo : ((j == jl + 1) ? hi : 0u);
    };

    auto stageA = [&](int buf, float xv0, float xv1) {
        unsigned int wd[8];
        char* a = arow[buf];
        buildwd(xv0, wd);
        *reinterpret_cast<uint4*>(a + cs0) = make_uint4(wd[0], wd[1], wd[2], wd[3]);
        *reinterpret_cast<uint4*>(a + cs1) = make_uint4(wd[4], wd[5], wd[6], wd[7]);
        buildwd(xv1, wd);
        *reinterpret_cast<uint4*>(a + cs2) = make_uint4(wd[0], wd[1], wd[2], wd[3]);
        *reinterpret_cast<uint4*>(a + cs3) = make_uint4(wd[4], wd[5], wd[6], wd[7]);
    };

    auto stageB = [&](int buf, int ktg) {
        const char* tb = (const char*)(Vp + ((size_t)(nt * 64 + ktg)) * 8192);
        char* lb = (char*)&Bs[buf][0];
#pragma unroll
        for (int r = 0; r < 4; ++r) {
            const char* g = tb + (r * 256 + t) * 16;
            unsigned ldsoff = (unsigned)((r * 256 + wid * 64) * 16);  // wave-uniform
            __builtin_amdgcn_global_load_lds(
                (const __attribute__((address_space(1))) unsigned int*)g,
                (__attribute__((address_space(3))) unsigned int*)(lb + ldsoff),
                16, 0, 0);
        }
    };

    // ---- prologue
    float2 xn = *reinterpret_cast<const float2*>(xp);
    stageB(0, kt0);
    stageA(0, xn.x, xn.y);
    xn = *reinterpret_cast<const float2*>(xp + 4);
    __syncthreads();

    for (int kt = 0; kt < ITERS; ++kt) {
        const int cur = kt & 1;

        // 1. issue next B-tile DMA early
        if (kt + 1 < ITERS) stageB(cur ^ 1, kt0 + kt + 1);

        // 2. fragment reads (16 x ds_read_b128)
        bf16x8 af[4][2], bg[4][2];
        const char* Ab = (const char*)&As[cur][0];
        const char* Bb = (const char*)&Bs[cur][0];
#pragma unroll
        for (int kh = 0; kh < 2; ++kh) {
            int k8 = kh * 4 + lhi;
#pragma unroll
            for (int mi = 0; mi < 4; ++mi) {
                int m = wm * 64 + mi * 16 + l15;
                af[mi][kh] = *reinterpret_cast<const bf16x8*>(
                    Ab + m * 128 + ((k8 ^ (m & 7)) * 16));
            }
#pragma unroll
            for (int ni = 0; ni < 4; ++ni) {
                int n = wn * 64 + ni * 16 + l15;
                bg[ni][kh] = *reinterpret_cast<const bf16x8*>(
                    Bb + n * 128 + ((k8 ^ (n & 7)) * 16));
            }
        }

        // 3. A-build for next tile + x prefetch (VALU overlaps ds_read latency)
        if (kt + 1 < ITERS) {
            stageA(cur ^ 1, xn.x, xn.y);
            if (kt + 2 < ITERS)
                xn = *reinterpret_cast<const float2*>(xp + (kt + 2) * 4);
        }

        // 4. 32 MFMA
#pragma unroll
        for (int mi = 0; mi < 4; ++mi)
#pragma unroll
            for (int ni = 0; ni < 4; ++ni)
#pragma unroll
                for (int kh = 0; kh < 2; ++kh)
                    acc[mi][ni] = __builtin_amdgcn_mfma_f32_16x16x32_bf16(
                        af[mi][kh], bg[ni][kh], acc[mi][ni], 0, 0, 0);

        // 5. single barrier per iter
        __syncthreads();
    }

    // ---- epilogue: atomic combine of K-split partials (+ skip_b once)
#pragma unroll
    for (int ni = 0; ni < 4; ++ni) {
        int col = oc0 + wn * 64 + ni * 16 + l15;
        float sb = (ks == 0) ? skip_b[col] : 0.f;
#pragma unroll
        for (int mi = 0; mi < 4; ++mi) {
            f32x4 v = acc[mi][ni];
            int row0 = bm0 + wm * 64 + mi * 16 + lhi * 4;
#pragma unroll
            for (int r = 0; r < 4; ++r)
                unsafeAtomicAdd(&out[(size_t)(row0 + r) * O_DIM + col], v[r] + sb);
        }
    }
}

extern "C" void kernel_launch(void* const* d_in, const int* in_sizes, int n_in,
                              void* d_out, int out_size, void* d_ws, size_t ws_size,
                              hipStream_t stream) {
    const float* x      = (const float*)d_in[0];   // [8192][256]
    const float* values = (const float*)d_in[1];   // [256][256][16]
    const float* skip_w = (const float*)d_in[2];   // [256][256]
    const float* skip_b = (const float*)d_in[3];   // [256]
    const float* gknots = (const float*)d_in[4];   // [16]
    float* out = (float*)d_out;
    unsigned short* Vp = (unsigned short*)d_ws;    // 2 MB bf16 scratch
    (void)in_sizes; (void)n_in; (void)out_size; (void)ws_size;

    // K-split partials are atomically accumulated -> out must start at zero.
    hipMemsetAsync(out, 0, (size_t)8192 * 256 * sizeof(float), stream);

    // Prep: 1,048,576 elements, 8 per thread
    kan_prep<<<dim3(512), dim3(256), 0, stream>>>(values, skip_w, gknots, Vp);

    // GEMM: 64 M-tiles x 2 N-tiles x 4 K-splits = 512 blocks (2/CU)
    kan_gemm<<<dim3(512), dim3(NTHREADS), 0, stream>>>(x, Vp, skip_b, out);
}